// Round 4
// baseline (192.332 us; speedup 1.0000x reference)
//
#include <hip/hip_runtime.h>

// GRU decoder via MFMA, round 8: B=32768, T=48, F=16, H=32.
// = round 7 + PREFETCH DEPTH 2: t-loop unrolled by 2 with two feat register
// pairs (pa0/pb0, pa1/pb1). Each step consumes regs prefetched TWO steps ago
// and issues the t+2 load, so the ~900-cycle HBM first-touch latency on the
// streamed feat rows is covered by two full steps of work instead of one.
// Side benefit: LDS buffer parity is now compile-time static (ds offsets fold
// into immediates).
// PAIR-SPLIT structure unchanged: block = 128 thr = 2 waves co-owning 16
// batch rows; wave w computes gate/hidden columns [16w,16w+16): 6 MFMAs + 4
// activation elements per lane per step. 2048 blocks = 8/CU exactly
// co-resident (4 waves/SIMD).
// Exchange of h_new (bf16 B-frag tile) + dense half-sums through
// double-buffered LDS with ONE raw s_barrier per step, preceded by
// s_waitcnt lgkmcnt(0) ONLY (imm 0xC07F) -- NOT __syncthreads(), whose
// vmcnt(0) would drain the feat prefetch every step (m97 barrier lesson).
// log2e folded into weights: sigmoid args pre-scaled by -log2(e), tanh arg
// by 2log2(e) -> every activation is rcp(1+exp2(x)) via v_exp_f32.
// Layouts (verified m89/m91/m120):
//   D[m=gatecol][n=batchcol]: col=lane&15=batch, row=(lane>>4)*4+reg=gatecol
//   A[m=lane&15][k=(lane>>4)*8+j] ; B[k=(lane>>4)*8+j][n=lane&15]

typedef __attribute__((ext_vector_type(8))) short short8;
typedef __attribute__((ext_vector_type(4))) float f32x4;

constexpr int T_STEPS  = 48;
constexpr int F_DIM    = 16;
constexpr int H_DIM    = 32;
constexpr int ROW_SH   = 40;              // shorts per h-row (80 B, 16B-aligned)
constexpr int HX_SH    = 16 * ROW_SH;     // one h buffer: 640 shorts
constexpr int O_STRIDE = 17;              // obuf leading stride (floats)

union S8 { short8 s; unsigned u[4]; };

__device__ __forceinline__ unsigned pk_bf16(float hi, float lo) {
    // (bf16(hi)<<16)|bf16(lo), round-half-up
    return __builtin_amdgcn_perm(__float_as_uint(hi) + 0x8000u,
                                 __float_as_uint(lo) + 0x8000u, 0x07060302u);
}
__device__ __forceinline__ short bf16s(float x) {
    return (short)((__float_as_uint(x) + 0x8000u) >> 16);
}
__device__ __forceinline__ float rcpf(float x) { return __builtin_amdgcn_rcpf(x); }
__device__ __forceinline__ float ex2(float x)  { return __builtin_amdgcn_exp2f(x); }
#define MFMA(a, b, c) __builtin_amdgcn_mfma_f32_16x16x32_bf16(a, b, c, 0, 0, 0)
#define SWZ16(v) __int_as_float(__builtin_amdgcn_ds_swizzle(__float_as_int(v), 0x401F))
#define BPERM(a, v) __builtin_amdgcn_ds_bpermute((a), (v))

__global__ __launch_bounds__(128, 4)
void gru_mfma8(const float* __restrict__ feat,     // [B,T,F]
               const float* __restrict__ init_in,  // [B,1]
               const float* __restrict__ init_h,   // [B,H]
               const float* __restrict__ Wk,       // [17,96]
               const float* __restrict__ Rk,       // [32,96]
               const float* __restrict__ bx,       // [96]
               const float* __restrict__ bh,       // [96]
               const float* __restrict__ dw,       // [32]
               const float* __restrict__ db,       // [1]
               float* __restrict__ out)            // [B,T]
{
    __shared__ __align__(16) short hx[2 * HX_SH];          // double-buffered h tile
    __shared__ float posum[2][2][16];                      // [parity][wave][col]
    __shared__ __align__(16) float obuf[T_STEPS * O_STRIDE];

    const int lane = threadIdx.x & 63;
    const int w    = threadIdx.x >> 6;        // 0/1: hidden half owned
    const int ln   = lane & 15;               // batch col
    const int quad = lane >> 4;
    const int b0   = blockIdx.x * 16;
    const int bpa  = (lane ^ 32) << 2;        // xor32 bpermute addr

    const float SZ = -1.44269504088896340736f;   // -log2(e)  (sigmoid args)
    const float SC =  2.88539008177792681472f;   // 2*log2(e) (tanh arg)

    // ---- weight fragments for this wave's hidden half (A-operand) ----
    S8 Wfz, Wfr, Wfh, Rfz, Rfr, Rfh;
#pragma unroll
    for (int j = 0; j < 8; ++j) {
        const int k = quad * 8 + j;
        const int n = w * 16 + ln;
        const float wz = (k < 16) ? SZ * Wk[(size_t)(k + 1) * 96 + n]      : 0.0f;
        const float wr = (k < 16) ? SZ * Wk[(size_t)(k + 1) * 96 + 32 + n] : 0.0f;
        const float wh = (k < 16) ? SC * Wk[(size_t)(k + 1) * 96 + 64 + n] : 0.0f;
        Wfz.s[j] = bf16s(wz); Wfr.s[j] = bf16s(wr); Wfh.s[j] = bf16s(wh);
        Rfz.s[j] = bf16s(SZ * Rk[(size_t)k * 96 + n]);
        Rfr.s[j] = bf16s(SZ * Rk[(size_t)k * 96 + 32 + n]);
        Rfh.s[j] = bf16s(SC * Rk[(size_t)k * 96 + 64 + n]);
    }

    // ---- per-lane constants for this wave's 4 gate elements ----
    float bz4[4], br4[4], bxh4[4], bhh4[4], wz4[4], wr4[4], wh4[4], dw4[4];
#pragma unroll
    for (int i = 0; i < 4; ++i) {
        const int c = w * 16 + quad * 4 + i;       // hidden unit index in [0,32)
        bz4[i]  = SZ * (bx[c] + bh[c]);
        br4[i]  = SZ * (bx[32 + c] + bh[32 + c]);
        bxh4[i] = SC * bx[64 + c];
        bhh4[i] = SC * bh[64 + c];
        wz4[i]  = SZ * Wk[c];                      // kernel row 0 = prev_out
        wr4[i]  = SZ * Wk[32 + c];
        wh4[i]  = SC * Wk[64 + c];
        dw4[i]  = dw[c];
    }
    const float dbs = db[0];

    // ---- initial state ----
    float hc[4];
#pragma unroll
    for (int i = 0; i < 4; ++i)
        hc[i] = init_h[(size_t)(b0 + ln) * H_DIM + w * 16 + quad * 4 + i];
    S8 hB;                                         // full-H B-frag (both halves)
    {
        const float* hp = init_h + (size_t)(b0 + ln) * H_DIM + quad * 8;
        const f32x4 a = *(const f32x4*)hp;
        const f32x4 b = *(const f32x4*)(hp + 4);
        hB.u[0] = pk_bf16(a[1], a[0]); hB.u[1] = pk_bf16(a[3], a[2]);
        hB.u[2] = pk_bf16(b[1], b[0]); hB.u[3] = pk_bf16(b[3], b[2]);
    }
    float po = init_in[b0 + ln];

    // ---- feat prefetch, depth 2 (both waves load twin rows -> L1 hits) ----
    const float* fqb = feat + (size_t)(b0 + ln) * (T_STEPS * F_DIM) + (quad & 1) * 8;
    f32x4 pa0 = *(const f32x4*)(fqb);
    f32x4 pb0 = *(const f32x4*)(fqb + 4);
    f32x4 pa1 = *(const f32x4*)(fqb + F_DIM);
    f32x4 pb1 = *(const f32x4*)(fqb + F_DIM + 4);

    // LDS addresses for the h exchange
    unsigned* hwr = (unsigned*)(hx + ln * ROW_SH + w * 16 + quad * 4);  // write own half
    const short8* hrd = (const short8*)(hx + ln * ROW_SH + quad * 8);   // read full

    // One GRU step. T_ = time index, P_ = LDS parity (literal 0/1 at each
    // call site -> static ds offsets), PA_/PB_ = feat regs for this step,
    // consumed then refilled with t+2 (prefetch depth 2).
#define GRU_STEP(T_, P_, PA_, PB_) do {                                        \
        S8 xa;                                                                 \
        xa.u[0] = pk_bf16(PA_[1], PA_[0]); xa.u[1] = pk_bf16(PA_[3], PA_[2]);  \
        xa.u[2] = pk_bf16(PB_[1], PB_[0]); xa.u[3] = pk_bf16(PB_[3], PB_[2]);  \
        const unsigned zm = (quad < 2) ? 0xFFFFFFFFu : 0u;                     \
        xa.u[0] &= zm; xa.u[1] &= zm; xa.u[2] &= zm; xa.u[3] &= zm;            \
        /* prefetch feat(T_+2) -- stays in flight across the raw barrier */    \
        const int t2 = ((T_) + 2 < T_STEPS) ? (T_) + 2 : T_STEPS - 1;          \
        PA_ = *(const f32x4*)(fqb + t2 * F_DIM);                               \
        PB_ = *(const f32x4*)(fqb + t2 * F_DIM + 4);                           \
        /* 6 MFMAs for this wave's hidden half */                              \
        f32x4 aZ  = {bz4[0],  bz4[1],  bz4[2],  bz4[3]};                       \
        f32x4 aR  = {br4[0],  br4[1],  br4[2],  br4[3]};                       \
        f32x4 aXH = {bxh4[0], bxh4[1], bxh4[2], bxh4[3]};                      \
        f32x4 aHH = {bhh4[0], bhh4[1], bhh4[2], bhh4[3]};                      \
        aZ  = MFMA(Wfz.s, xa.s, aZ);                                           \
        aR  = MFMA(Wfr.s, xa.s, aR);                                           \
        aXH = MFMA(Wfh.s, xa.s, aXH);                                          \
        aZ  = MFMA(Rfz.s, hB.s, aZ);                                           \
        aR  = MFMA(Rfr.s, hB.s, aR);                                           \
        aHH = MFMA(Rfh.s, hB.s, aHH);                                          \
        /* gates (pre-scaled: activation = rcp(1+exp2(x))) */                  \
        float hn[4];                                                           \
        _Pragma("unroll")                                                      \
        for (int i = 0; i < 4; ++i) {                                          \
            const float zz = rcpf(1.0f + ex2(fmaf(po, wz4[i], aZ[i])));        \
            const float rr = rcpf(1.0f + ex2(fmaf(po, wr4[i], aR[i])));        \
            const float vv = fmaf(rr, aHH[i], fmaf(po, wh4[i], aXH[i]));       \
            const float cc = fmaf(-2.0f, rcpf(1.0f + ex2(vv)), 1.0f);          \
            const float h2 = cc + zz * (hc[i] - cc);                           \
            hc[i] = h2;                                                        \
            hn[i] = h2;                                                        \
        }                                                                      \
        /* dense half-sum over this wave's 16 hidden units */                  \
        const float d01 = fmaf(hn[0], dw4[0], hn[1] * dw4[1]);                 \
        const float d23 = fmaf(hn[2], dw4[2], hn[3] * dw4[3]);                 \
        float s = d01 + d23;                                                   \
        s += SWZ16(s);                                                         \
        s += __int_as_float(BPERM(bpa, __float_as_int(s)));                    \
        /* publish own half: h_new (2x packed u32) + half-sum */               \
        unsigned* hw = hwr + (P_) * (HX_SH / 2);                               \
        hw[0] = pk_bf16(hn[1], hn[0]);                                         \
        hw[1] = pk_bf16(hn[3], hn[2]);                                         \
        if (lane < 16) posum[P_][w][lane] = s;                                 \
        /* ONE raw barrier: wait DS writes (lgkm only), NOT the prefetch */    \
        __builtin_amdgcn_s_waitcnt(0xC07F);                                    \
        __builtin_amdgcn_s_barrier();                                          \
        /* read full h B-frag + other half-sum */                              \
        hB.s = hrd[(P_) * (HX_SH / 8)];                                        \
        const float os = posum[P_][1 - w][ln];                                 \
        po = s + os + dbs;                                                     \
        if (w == 0 && lane < 16) obuf[(T_) * O_STRIDE + lane] = po;            \
    } while (0)

    for (int t = 0; t < T_STEPS; t += 2) {
        GRU_STEP(t,     0, pa0, pb0);
        GRU_STEP(t + 1, 1, pa1, pb1);
    }
#undef GRU_STEP

    // ---- flush outputs (wave 0): coalesced dwordx4 ----
    if (w == 0) {
        const int row = lane >> 2;                 // 0..15
        const int tb  = (lane & 3) * 12;           // 0,12,24,36
        float* orow = out + (size_t)(b0 + row) * T_STEPS + tb;
#pragma unroll
        for (int k = 0; k < 3; ++k) {
            f32x4 v;
#pragma unroll
            for (int e = 0; e < 4; ++e) v[e] = obuf[(tb + k * 4 + e) * O_STRIDE + row];
            *(f32x4*)(orow + k * 4) = v;
        }
    }
}

extern "C" void kernel_launch(void* const* d_in, const int* in_sizes, int n_in,
                              void* d_out, int out_size, void* d_ws, size_t ws_size,
                              hipStream_t stream) {
    const float* feat    = (const float*)d_in[0];
    const float* init_in = (const float*)d_in[1];
    const float* init_h  = (const float*)d_in[2];
    const float* Wk      = (const float*)d_in[3];
    const float* Rk      = (const float*)d_in[4];
    const float* bx      = (const float*)d_in[5];
    const float* bh      = (const float*)d_in[6];
    const float* dw      = (const float*)d_in[7];
    const float* db      = (const float*)d_in[8];
    float* out           = (float*)d_out;

    const int B = in_sizes[2] / H_DIM;      // 32768
    dim3 grid((unsigned)(B / 16));          // one 2-wave block per 16 batch rows
    dim3 block(128);
    hipLaunchKernelGGL(gru_mfma8, grid, block, 0, stream,
                       feat, init_in, init_h, Wk, Rk, bx, bh, dw, db, out);
}